// Round 2
// baseline (811.200 us; speedup 1.0000x reference)
//
#include <hip/hip_runtime.h>
#include <cstdint>

#define M_DIM 16384
#define N_DIM 4096
#define K_DIM 4096

#define BM 128
#define BN 128
#define BK 128  // int8 K-tile bytes per row; 32 KB LDS total, 32 MFMA/barrier

typedef __attribute__((ext_vector_type(4))) int int32x4;

#define GLLD16(g, l)                                              \
  __builtin_amdgcn_global_load_lds(                               \
      (const __attribute__((address_space(1))) void*)(g),         \
      (__attribute__((address_space(3))) void*)(l), 16, 0, 0)

// ---------------------------------------------------------------------------
// Kernel 1: quantize activations. Unit-stride per instruction: lane reads
// float4 at [base + i*256 + tid] (1 KB contiguous per wave-instr), stores
// the packed 4 bytes as one dword at the same element position.
// ---------------------------------------------------------------------------
__global__ void quant_x_kernel(const float* __restrict__ x,
                               const float* __restrict__ sp,
                               const int* __restrict__ zpp,
                               int8_t* __restrict__ qx) {
  const float inv = 1.0f / sp[0];
  const int zp = zpp[0];
  const int tid = threadIdx.x;
  const int base = blockIdx.x * 1024;  // in float4 units
  const float4* x4 = (const float4*)x;
  unsigned* q4 = (unsigned*)qx;
#pragma unroll
  for (int i = 0; i < 4; i++) {
    const int idx = base + i * 256 + tid;
    float4 v = x4[idx];
    int q0 = min(127, max(-128, (int)rintf(v.x * inv) + zp));
    int q1 = min(127, max(-128, (int)rintf(v.y * inv) + zp));
    int q2 = min(127, max(-128, (int)rintf(v.z * inv) + zp));
    int q3 = min(127, max(-128, (int)rintf(v.w * inv) + zp));
    q4[idx] = (unsigned)(q0 & 255) | ((unsigned)(q1 & 255) << 8) |
              ((unsigned)(q2 & 255) << 16) | ((unsigned)(q3 & 255) << 24);
  }
}

// ---------------------------------------------------------------------------
// Kernel 2: quantize weights (one block per output channel n), compute
// wsum[n] = sum_k qw[n,k], then cs[n] = s*ws[n], off[n] = bias - zp*wsum*cs.
// ---------------------------------------------------------------------------
__global__ void quant_w_kernel(const float* __restrict__ w,
                               const float* __restrict__ wscale,
                               const float* __restrict__ bias,
                               const float* __restrict__ sp,
                               const int* __restrict__ zpp,
                               int8_t* __restrict__ qw,
                               float* __restrict__ cs,
                               float* __restrict__ off) {
  const int n = blockIdx.x;
  const float ws = wscale[n];
  const float invw = 1.0f / ws;
  const float s = sp[0];
  const int zp = zpp[0];
  const float4* wr = (const float4*)(w + (size_t)n * K_DIM);
  unsigned* qr = (unsigned*)(qw + (size_t)n * K_DIM);
  int sum = 0;
#pragma unroll
  for (int it = 0; it < K_DIM / (256 * 4); it++) {
    const int idx = it * 256 + threadIdx.x;
    float4 v = wr[idx];
    int q0 = min(127, max(-128, (int)rintf(v.x * invw)));
    int q1 = min(127, max(-128, (int)rintf(v.y * invw)));
    int q2 = min(127, max(-128, (int)rintf(v.z * invw)));
    int q3 = min(127, max(-128, (int)rintf(v.w * invw)));
    sum += q0 + q1 + q2 + q3;
    qr[idx] = (unsigned)(q0 & 255) | ((unsigned)(q1 & 255) << 8) |
              ((unsigned)(q2 & 255) << 16) | ((unsigned)(q3 & 255) << 24);
  }
  __shared__ int red[4];
#pragma unroll
  for (int o = 32; o > 0; o >>= 1) sum += __shfl_down(sum, o, 64);
  if ((threadIdx.x & 63) == 0) red[threadIdx.x >> 6] = sum;
  __syncthreads();
  if (threadIdx.x == 0) {
    const int tot = red[0] + red[1] + red[2] + red[3];
    const float c = s * ws;
    cs[n] = c;
    off[n] = bias[n] - (float)(zp * tot) * c;
  }
}

// ---------------------------------------------------------------------------
// Kernel 3: int8 GEMM. Block = 256 thr = 4 waves, tile 128x128, BK=128.
// Per iter per wave: 8 global_load_lds_dwordx4, 16 ds_read_b128, 32 MFMA
// (16x16x64_i8). 32 MFMA per barrier-pair (2x round 1) amortizes the
// vmcnt(0)-drain stall. LDS rows are 128 B (8 x 16 B chunks); chunk c of
// row r stored at position c ^ (r & 7) — without the XOR, row number drops
// out of the bank index entirely (128 B = exactly 32 banks) -> 16-way
// conflict on fragment reads.
// ---------------------------------------------------------------------------
__global__ __launch_bounds__(256) void gemm_i8(
    const int8_t* __restrict__ qx, const int8_t* __restrict__ qw,
    const float* __restrict__ cs, const float* __restrict__ off,
    float* __restrict__ out) {
  __shared__ __align__(16) int8_t As[BM * BK];  // 16 KB
  __shared__ __align__(16) int8_t Bs[BN * BK];  // 16 KB

  const int tid = threadIdx.x;
  const int lane = tid & 63;
  const int wave = tid >> 6;  // 0..3
  const int wm = wave >> 1;   // 0..1
  const int wn = wave & 1;    // 0..1

  const int n0 = blockIdx.x * BN;
  const int m0 = blockIdx.y * BM;

  int32x4 acc[4][4] = {};

  // ---- staging: 16 segments of 1 KB (g=0..3 rounds x 4 waves) ----
  // segment byte o covers LDS rows [o>>7 .. o>>7+8); lane's slot holds
  // logical chunk c = ((o>>4)&7) ^ (row&7) of global row (m0/n0 + row).
  const int8_t* gA[4];
  const int8_t* gB[4];
  int lof[4];
#pragma unroll
  for (int g = 0; g < 4; g++) {
    const int o = g * 4096 + wave * 1024 + lane * 16;
    const int r = o >> 7;
    const int c = ((o >> 4) & 7) ^ (r & 7);
    gA[g] = qx + (size_t)(m0 + r) * K_DIM + c * 16;
    gB[g] = qw + (size_t)(n0 + r) * K_DIM + c * 16;
    lof[g] = g * 4096 + wave * 1024;  // wave-uniform LDS base
  }

  // ---- fragment read offsets ----
  const int fr = lane & 15;    // row within 16-tile (m or n)
  const int quad = lane >> 4;  // k-sub-chunk (k = quad*16 + j within 64)
  int aoff[2][4], boff[2][4];
#pragma unroll
  for (int ks = 0; ks < 2; ks++) {
#pragma unroll
    for (int t = 0; t < 4; t++) {
      const int ar = wm * 64 + t * 16 + fr;
      const int br = wn * 64 + t * 16 + fr;
      const int c = ks * 4 + quad;  // logical chunk within the 128 B row
      aoff[ks][t] = ar * BK + (c ^ (ar & 7)) * 16;
      boff[ks][t] = br * BK + (c ^ (br & 7)) * 16;
    }
  }

  for (int kt = 0; kt < K_DIM; kt += BK) {
    __syncthreads();  // previous iteration's LDS reads complete
#pragma unroll
    for (int g = 0; g < 4; g++) GLLD16(gA[g] + kt, As + lof[g]);
#pragma unroll
    for (int g = 0; g < 4; g++) GLLD16(gB[g] + kt, Bs + lof[g]);
    __syncthreads();  // drains vmcnt(0) before use

#pragma unroll
    for (int ks = 0; ks < 2; ks++) {
      int32x4 af[4], bf[4];
#pragma unroll
      for (int t = 0; t < 4; t++) {
        af[t] = *(const int32x4*)(As + aoff[ks][t]);
        bf[t] = *(const int32x4*)(Bs + boff[ks][t]);
      }
#pragma unroll
      for (int tm = 0; tm < 4; tm++)
#pragma unroll
        for (int tn = 0; tn < 4; tn++)
          acc[tm][tn] = __builtin_amdgcn_mfma_i32_16x16x64_i8(
              af[tm], bf[tn], acc[tm][tn], 0, 0, 0);
    }
  }

  // ---- epilogue: out = acc * cs[col] + off[col] ----
#pragma unroll
  for (int tn = 0; tn < 4; tn++) {
    const int col = n0 + wn * 64 + tn * 16 + fr;
    const float c = cs[col];
    const float o = off[col];
#pragma unroll
    for (int tm = 0; tm < 4; tm++) {
      const int rowb = m0 + wm * 64 + tm * 16 + quad * 4;
#pragma unroll
      for (int r = 0; r < 4; r++) {
        out[(size_t)(rowb + r) * N_DIM + col] = (float)acc[tm][tn][r] * c + o;
      }
    }
  }
}

// ---------------------------------------------------------------------------
extern "C" void kernel_launch(void* const* d_in, const int* in_sizes, int n_in,
                              void* d_out, int out_size, void* d_ws,
                              size_t ws_size, hipStream_t stream) {
  const float* x = (const float*)d_in[0];
  const float* w = (const float*)d_in[1];
  const float* bias = (const float*)d_in[2];
  const float* act_scale = (const float*)d_in[3];
  const int* zp = (const int*)d_in[4];
  const float* wscale = (const float*)d_in[5];
  float* out = (float*)d_out;

  int8_t* qx = (int8_t*)d_ws;                          // 64 MB
  int8_t* qw = qx + (size_t)M_DIM * K_DIM;             // 16 MB
  float* cs = (float*)(qw + (size_t)N_DIM * K_DIM);    // 16 KB
  float* off = cs + N_DIM;                             // 16 KB

  quant_x_kernel<<<16384, 256, 0, stream>>>(x, act_scale, zp, qx);
  quant_w_kernel<<<N_DIM, 256, 0, stream>>>(w, wscale, bias, act_scale, zp,
                                            qw, cs, off);
  gemm_i8<<<dim3(N_DIM / BN, M_DIM / BM), 256, 0, stream>>>(qx, qw, cs, off,
                                                            out);
}